// Round 5
// baseline (348.406 us; speedup 1.0000x reference)
//
#include <hip/hip_runtime.h>

#define IN_DIM   2048
#define OUT_DIM  4096
#define MEM_LEN  32768
#define BETA     5000.0f

typedef float f4v  __attribute__((ext_vector_type(4)));
typedef f4v   uf4  __attribute__((aligned(4)));   // 4B-aligned float4 (gfx9+ allows dword-aligned dwordx4)

// workspace layout (float offsets), ~5.03 MB total
#define WS_PS    0                         // [256][2048] stats partial sums
#define WS_PQ    (WS_PS + 256*2048)        // [256][2048] stats partial sum-squares
#define WS_PG    (WS_PQ + 256*2048)        // [64][4096]  gemv partials
#define WS_NEW   (WS_PG + 64*4096)         // [2048] normalized query
#define WS_ENC   (WS_NEW + 2048)           // [4096] tanh(enc)
#define WS_MINB  (WS_ENC + 4096)           // [64] bucket minima (float bits as uint)

// ---------------- fused: column partial stats of mem_data + copy to out
// grid (2,256), block 256. Thread owns shifted window cols [4g-1 .. 4g+2]
// (g = bx*256+t, 512 windows/row), 128-row chunk per blockIdx.y.
// Load: one 4B-aligned dwordx4 (input). Store: 16B-aligned dwordx4 (output
// base is +1 float, so col 4g-1 is 16B-aligned there). Head thread (g==0)
// covers cols 0..2, tail thread (g==511) additionally col 2047.
__global__ void k_stats_copy(const float* __restrict__ md,
                             float* __restrict__ out_md,
                             float* __restrict__ ws) {
    const int g = blockIdx.x * 256 + threadIdx.x;   // 0..511
    const bool head = (g == 0), tail = (g == 511);
    const int cbase = head ? 0 : 4 * g - 1;
    const int r0 = blockIdx.y * 128;
    f4v s = {0.f,0.f,0.f,0.f}, q = {0.f,0.f,0.f,0.f};
    float s4 = 0.f, q4 = 0.f;
#pragma unroll 4
    for (int i = 0; i < 128; ++i) {
        const size_t r = (size_t)(r0 + i);
        const float* irow = md + r * IN_DIM;
        float*       orow = out_md + r * IN_DIM;
        uf4 v = *(const uf4*)(irow + cbase);
        if (head) v.w = 0.0f;               // col 3 belongs to g==1
        s += v; q += v * v;
        if (head) {
            orow[0] = v.x; orow[1] = v.y; orow[2] = v.z;
        } else {
            *(uf4*)(orow + cbase) = v;
        }
        if (tail) {
            float m = irow[IN_DIM - 1];
            s4 += m; q4 += m * m;
            orow[IN_DIM - 1] = m;
        }
    }
    float* ps = ws + WS_PS + blockIdx.y * IN_DIM;
    float* pq = ws + WS_PQ + blockIdx.y * IN_DIM;
    if (head) {
        ps[0] = s.x; ps[1] = s.y; ps[2] = s.z;
        pq[0] = q.x; pq[1] = q.y; pq[2] = q.z;
    } else {
        *(uf4*)(ps + cbase) = s;
        *(uf4*)(pq + cbase) = q;
    }
    if (tail) { ps[IN_DIM - 1] = s4; pq[IN_DIM - 1] = q4; }
}

// ------------------------- new = (x-mean)/std  (+ min-bucket init)
// grid 64, block 256 = 32 columns x 8 y-threads; each y-thread sums 32
// partials; LDS [8][32] combine. Wave reads 2 x 128B segments per step.
__global__ void k_new(const float* __restrict__ x, float* __restrict__ ws) {
    const int cl = threadIdx.x & 31;
    const int yt = threadIdx.x >> 5;            // 0..7
    const int c  = blockIdx.x * 32 + cl;
    if (blockIdx.x == 0 && threadIdx.x < 64)
        ((unsigned int*)ws)[WS_MINB + threadIdx.x] = 0x7F800000u;  // +inf
    float s = 0.0f, q = 0.0f;
#pragma unroll 8
    for (int k = 0; k < 32; ++k) {
        int y = yt * 32 + k;
        s += ws[WS_PS + y * IN_DIM + c];
        q += ws[WS_PQ + y * IN_DIM + c];
    }
    __shared__ float rs[8][32], rq[8][32];
    rs[yt][cl] = s; rq[yt][cl] = q;
    __syncthreads();
    if (threadIdx.x < 32) {
        const int cc = blockIdx.x * 32 + threadIdx.x;
        float S = 0.0f, Q = 0.0f;
#pragma unroll
        for (int y8 = 0; y8 < 8; ++y8) { S += rs[y8][threadIdx.x]; Q += rq[y8][threadIdx.x]; }
        float mean = S * (1.0f / (float)MEM_LEN);
        float var  = (Q - S * mean) * (1.0f / (float)(MEM_LEN - 1));  // ddof=1
        float sd   = sqrtf(fmaxf(var, 0.0f));
        ws[WS_NEW + cc] = (sd == 0.0f) ? 0.0f : (x[cc] - mean) / sd;
    }
}

// ---------------------------------------------------------------- GEMV partials
__global__ void k_gemv(const float* __restrict__ W, float* __restrict__ ws) {
    const int j4 = blockIdx.x * 256 + threadIdx.x;    // 0..1023
    const int i0 = blockIdx.y * 32;
    const f4v* W4 = (const f4v*)W;
    f4v a = {0.f, 0.f, 0.f, 0.f};
#pragma unroll 8
    for (int k = 0; k < 32; ++k) {
        float nv = ws[WS_NEW + i0 + k];
        f4v w = W4[(size_t)(i0 + k) * 1024 + j4];
        a += nv * w;
    }
    ((f4v*)(ws + WS_PG))[(size_t)blockIdx.y * 1024 + j4] = a;
}

// ------------------------------------------------ reduce gemv + bias + tanh
// grid 64, block 256 = 64 j x 4 y-threads; each sums 16 partials; LDS combine.
__global__ void k_enc(const float* __restrict__ b_enc, float* __restrict__ ws) {
    const int jl = threadIdx.x & 63;
    const int yt = threadIdx.x >> 6;            // 0..3
    const int j  = blockIdx.x * 64 + jl;
    float s = 0.0f;
#pragma unroll 4
    for (int k = 0; k < 16; ++k) {
        int y = yt * 16 + k;
        s += ws[WS_PG + y * OUT_DIM + j];
    }
    __shared__ float r[4][64];
    r[yt][jl] = s;
    __syncthreads();
    if (threadIdx.x < 64) {
        const int jj = blockIdx.x * 64 + threadIdx.x;
        float S = b_enc[jj] + r[0][threadIdx.x] + r[1][threadIdx.x]
                + r[2][threadIdx.x] + r[3][threadIdx.x];
        ws[WS_ENC + jj] = tanhf(S);
    }
}

// ------------------- fused: per-row L1 distance + copy memory to out
// Wave per row (block 256 = 4 rows, grid 8192). Shifted-window trick:
// thread g loads cols [4g-1..4g+2] (4B-aligned dwordx4), stores them
// 16B-aligned in output space. Head covers cols 0..2, tail also col 4095.
__global__ void k_dist_copy(const float* __restrict__ mem,
                            float* __restrict__ out_mem,
                            float* __restrict__ ws) {
    const int lane = threadIdx.x & 63;
    const int wid  = threadIdx.x >> 6;
    const size_t r = (size_t)blockIdx.x * 4 + wid;
    const float* irow = mem + r * OUT_DIM;
    float*       orow = out_mem + r * OUT_DIM;
    const float* enc  = ws + WS_ENC;
    float acc = 0.0f;
#pragma unroll 4
    for (int k = 0; k < 16; ++k) {
        const int g = k * 64 + lane;           // 0..1023
        const bool head = (g == 0), tail = (g == 1023);
        const int cbase = head ? 0 : 4 * g - 1;
        uf4 v = *(const uf4*)(irow + cbase);
        uf4 e = *(const uf4*)(enc + cbase);
        float aw = head ? 0.0f : fabsf(v.w - e.w);   // col 3 belongs to g==1
        acc += fabsf(v.x - e.x) + fabsf(v.y - e.y) + fabsf(v.z - e.z) + aw;
        if (head) {
            orow[0] = v.x; orow[1] = v.y; orow[2] = v.z;
        } else {
            *(uf4*)(orow + cbase) = v;
        }
        if (tail) {
            float m = irow[OUT_DIM - 1];
            acc += fabsf(m - enc[OUT_DIM - 1]);
            orow[OUT_DIM - 1] = m;
        }
    }
    for (int off = 32; off >= 1; off >>= 1)
        acc += __shfl_down(acc, off, 64);
    __shared__ float wmin[4];
    if (lane == 0) wmin[wid] = acc;
    __syncthreads();
    if (threadIdx.x == 0) {
        float b = fminf(fminf(wmin[0], wmin[1]), fminf(wmin[2], wmin[3]));
        atomicMin((unsigned int*)ws + WS_MINB + (blockIdx.x & 63),
                  __float_as_uint(b));   // b >= 0 so uint-order == float-order
    }
}

// ---------------------------------------------------------------- finalize
__global__ void k_final(const float* __restrict__ x, const int* __restrict__ count,
                        const float* __restrict__ ws, float* __restrict__ d_out) {
    __shared__ float sl;
    int t = threadIdx.x;
    if (t < 64) {
        float v = __uint_as_float(((const unsigned int*)ws)[WS_MINB + t]);
        for (int off = 32; off >= 1; off >>= 1)
            v = fminf(v, __shfl_down(v, off, 64));
        if (t == 0) { d_out[0] = v; sl = v; }
    }
    __syncthreads();
    float loss = sl;
    if (loss <= BETA) {
        int pos = count[0] % MEM_LEN;
        float* outM  = d_out + 1;
        float* outMD = d_out + 1 + (size_t)MEM_LEN * OUT_DIM;
        for (int j = t; j < OUT_DIM; j += 256)
            outM[(size_t)pos * OUT_DIM + j] = ws[WS_ENC + j];
        for (int i = t; i < IN_DIM; i += 256)
            outMD[(size_t)pos * IN_DIM + i] = x[i];
    }
}

extern "C" void kernel_launch(void* const* d_in, const int* in_sizes, int n_in,
                              void* d_out, int out_size, void* d_ws, size_t ws_size,
                              hipStream_t stream) {
    const float* x        = (const float*)d_in[0];
    const float* memory   = (const float*)d_in[1];
    const float* mem_data = (const float*)d_in[2];
    const float* W_enc    = (const float*)d_in[3];
    const float* b_enc    = (const float*)d_in[4];
    const int*   count    = (const int*)d_in[5];
    float* out = (float*)d_out;
    float* ws  = (float*)d_ws;

    float* out_mem = out + 1;                                   // [32768][4096]
    float* out_md  = out + 1 + (size_t)MEM_LEN * OUT_DIM;       // [32768][2048]

    k_stats_copy<<<dim3(2, 256), 256, 0, stream>>>(mem_data, out_md, ws);
    k_new<<<64, 256, 0, stream>>>(x, ws);
    k_gemv<<<dim3(4, 64), 256, 0, stream>>>(W_enc, ws);
    k_enc<<<64, 256, 0, stream>>>(b_enc, ws);
    k_dist_copy<<<8192, 256, 0, stream>>>(memory, out_mem, ws);
    k_final<<<1, 256, 0, stream>>>(x, count, ws, out);
}

// Round 6
// 336.582 us; speedup vs baseline: 1.0351x; 1.0351x over previous
//
#include <hip/hip_runtime.h>

#define IN_DIM   2048
#define OUT_DIM  4096
#define MEM_LEN  32768
#define BETA     5000.0f

typedef float f4v  __attribute__((ext_vector_type(4)));
typedef f4v   uf4  __attribute__((aligned(4)));   // 4B-aligned float4 (gfx9 flat/global supports unaligned)

// workspace layout (float offsets), ~5.03 MB total
#define WS_PS    0                         // [256][2048] stats partial sums
#define WS_PQ    (WS_PS + 256*2048)        // [256][2048] stats partial sum-squares
#define WS_PG    (WS_PQ + 256*2048)        // [64][4096]  gemv partials
#define WS_NEW   (WS_PG + 64*4096)         // [2048] normalized query
#define WS_ENC   (WS_NEW + 2048)           // [4096] tanh(enc)
#define WS_MINB  (WS_ENC + 4096)           // [64] bucket minima (float bits as uint)

// ---------------- fused: column partial stats of mem_data + copy to out
// grid (2,256), block 256. Thread owns ALIGNED input cols [4g..4g+3]
// (g = bx*256+t, 512 groups/row), 128-row chunk per blockIdx.y.
// Load: aligned dwordx4. Store: same logical cols in output space, whose
// row base is +1 float -> byte offset ==4 mod 16 (misaligned dwordx4 store,
// absorbed by the write path). No head/tail branches; stores tile the row.
__global__ void k_stats_copy(const float* __restrict__ md,
                             float* __restrict__ out_md,
                             float* __restrict__ ws) {
    const int g  = blockIdx.x * 256 + threadIdx.x;   // 0..511
    const int r0 = blockIdx.y * 128;
    const f4v* in4 = (const f4v*)md;
    f4v s = {0.f,0.f,0.f,0.f}, q = {0.f,0.f,0.f,0.f};
#pragma unroll 8
    for (int i = 0; i < 128; ++i) {
        const size_t r = (size_t)(r0 + i);
        f4v v = in4[r * 512 + g];                    // aligned 16B load
        s += v; q += v * v;
        *(uf4*)(out_md + r * IN_DIM + 4 * g) = v;    // misaligned 16B store
    }
    ((f4v*)(ws + WS_PS + (size_t)blockIdx.y * IN_DIM))[g] = s;   // aligned
    ((f4v*)(ws + WS_PQ + (size_t)blockIdx.y * IN_DIM))[g] = q;
}

// ------------------------- new = (x-mean)/std  (+ min-bucket init)
// grid 64, block 256 = 32 columns x 8 y-threads; LDS combine.
__global__ void k_new(const float* __restrict__ x, float* __restrict__ ws) {
    const int cl = threadIdx.x & 31;
    const int yt = threadIdx.x >> 5;            // 0..7
    const int c  = blockIdx.x * 32 + cl;
    if (blockIdx.x == 0 && threadIdx.x < 64)
        ((unsigned int*)ws)[WS_MINB + threadIdx.x] = 0x7F800000u;  // +inf
    float s = 0.0f, q = 0.0f;
#pragma unroll 8
    for (int k = 0; k < 32; ++k) {
        int y = yt * 32 + k;
        s += ws[WS_PS + y * IN_DIM + c];
        q += ws[WS_PQ + y * IN_DIM + c];
    }
    __shared__ float rs[8][32], rq[8][32];
    rs[yt][cl] = s; rq[yt][cl] = q;
    __syncthreads();
    if (threadIdx.x < 32) {
        const int cc = blockIdx.x * 32 + threadIdx.x;
        float S = 0.0f, Q = 0.0f;
#pragma unroll
        for (int y8 = 0; y8 < 8; ++y8) { S += rs[y8][threadIdx.x]; Q += rq[y8][threadIdx.x]; }
        float mean = S * (1.0f / (float)MEM_LEN);
        float var  = (Q - S * mean) * (1.0f / (float)(MEM_LEN - 1));  // ddof=1
        float sd   = sqrtf(fmaxf(var, 0.0f));
        ws[WS_NEW + cc] = (sd == 0.0f) ? 0.0f : (x[cc] - mean) / sd;
    }
}

// ---------------------------------------------------------------- GEMV partials
__global__ void k_gemv(const float* __restrict__ W, float* __restrict__ ws) {
    const int j4 = blockIdx.x * 256 + threadIdx.x;    // 0..1023
    const int i0 = blockIdx.y * 32;
    const f4v* W4 = (const f4v*)W;
    f4v a = {0.f, 0.f, 0.f, 0.f};
#pragma unroll 8
    for (int k = 0; k < 32; ++k) {
        float nv = ws[WS_NEW + i0 + k];
        f4v w = W4[(size_t)(i0 + k) * 1024 + j4];
        a += nv * w;
    }
    ((f4v*)(ws + WS_PG))[(size_t)blockIdx.y * 1024 + j4] = a;
}

// ------------------------------------------------ reduce gemv + bias + tanh
// grid 64, block 256 = 64 j x 4 y-threads; LDS combine.
__global__ void k_enc(const float* __restrict__ b_enc, float* __restrict__ ws) {
    const int jl = threadIdx.x & 63;
    const int yt = threadIdx.x >> 6;            // 0..3
    const int j  = blockIdx.x * 64 + jl;
    float s = 0.0f;
#pragma unroll 4
    for (int k = 0; k < 16; ++k) {
        int y = yt * 16 + k;
        s += ws[WS_PG + y * OUT_DIM + j];
    }
    __shared__ float r[4][64];
    r[yt][jl] = s;
    __syncthreads();
    if (threadIdx.x < 64) {
        const int jj = blockIdx.x * 64 + threadIdx.x;
        float S = b_enc[jj] + r[0][threadIdx.x] + r[1][threadIdx.x]
                + r[2][threadIdx.x] + r[3][threadIdx.x];
        ws[WS_ENC + jj] = tanhf(S);
    }
}

// ------------------- fused: per-row L1 distance + copy memory to out
// Wave per row (block 256 = 4 rows, grid 8192). Thread g: ALIGNED load of
// cols [4g..4g+3], misaligned dwordx4 store to output (+4B base). enc is
// staged once per block into LDS (16 KB) -> aligned conflict-free b128
// reads, removing the third VMEM stream from the hot loop.
__global__ void k_dist_copy(const float* __restrict__ mem,
                            float* __restrict__ out_mem,
                            float* __restrict__ ws) {
    __shared__ f4v enc_l[1024];                 // 4096 floats = 16 KB
    const f4v* e4 = (const f4v*)(ws + WS_ENC);
#pragma unroll
    for (int i = 0; i < 4; ++i)
        enc_l[threadIdx.x + 256 * i] = e4[threadIdx.x + 256 * i];
    __syncthreads();

    const int lane = threadIdx.x & 63;
    const int wid  = threadIdx.x >> 6;
    const size_t r = (size_t)blockIdx.x * 4 + wid;
    const f4v* irow4 = (const f4v*)mem + r * 1024;
    float*     orow  = out_mem + r * OUT_DIM;
    float acc = 0.0f;
#pragma unroll 4
    for (int k = 0; k < 16; ++k) {
        const int g = k * 64 + lane;           // 0..1023
        f4v v = irow4[g];                      // aligned 16B load
        f4v e = enc_l[g];                      // LDS, conflict-free
        acc += fabsf(v.x - e.x) + fabsf(v.y - e.y) +
               fabsf(v.z - e.z) + fabsf(v.w - e.w);
        *(uf4*)(orow + 4 * g) = v;             // misaligned 16B store
    }
    for (int off = 32; off >= 1; off >>= 1)
        acc += __shfl_down(acc, off, 64);
    __shared__ float wmin[4];
    if (lane == 0) wmin[wid] = acc;
    __syncthreads();
    if (threadIdx.x == 0) {
        float b = fminf(fminf(wmin[0], wmin[1]), fminf(wmin[2], wmin[3]));
        atomicMin((unsigned int*)ws + WS_MINB + (blockIdx.x & 63),
                  __float_as_uint(b));   // b >= 0 so uint-order == float-order
    }
}

// ---------------------------------------------------------------- finalize
__global__ void k_final(const float* __restrict__ x, const int* __restrict__ count,
                        const float* __restrict__ ws, float* __restrict__ d_out) {
    __shared__ float sl;
    int t = threadIdx.x;
    if (t < 64) {
        float v = __uint_as_float(((const unsigned int*)ws)[WS_MINB + t]);
        for (int off = 32; off >= 1; off >>= 1)
            v = fminf(v, __shfl_down(v, off, 64));
        if (t == 0) { d_out[0] = v; sl = v; }
    }
    __syncthreads();
    float loss = sl;
    if (loss <= BETA) {
        int pos = count[0] % MEM_LEN;
        float* outM  = d_out + 1;
        float* outMD = d_out + 1 + (size_t)MEM_LEN * OUT_DIM;
        for (int j = t; j < OUT_DIM; j += 256)
            outM[(size_t)pos * OUT_DIM + j] = ws[WS_ENC + j];
        for (int i = t; i < IN_DIM; i += 256)
            outMD[(size_t)pos * IN_DIM + i] = x[i];
    }
}

extern "C" void kernel_launch(void* const* d_in, const int* in_sizes, int n_in,
                              void* d_out, int out_size, void* d_ws, size_t ws_size,
                              hipStream_t stream) {
    const float* x        = (const float*)d_in[0];
    const float* memory   = (const float*)d_in[1];
    const float* mem_data = (const float*)d_in[2];
    const float* W_enc    = (const float*)d_in[3];
    const float* b_enc    = (const float*)d_in[4];
    const int*   count    = (const int*)d_in[5];
    float* out = (float*)d_out;
    float* ws  = (float*)d_ws;

    float* out_mem = out + 1;                                   // [32768][4096]
    float* out_md  = out + 1 + (size_t)MEM_LEN * OUT_DIM;       // [32768][2048]

    k_stats_copy<<<dim3(2, 256), 256, 0, stream>>>(mem_data, out_md, ws);
    k_new<<<64, 256, 0, stream>>>(x, ws);
    k_gemv<<<dim3(4, 64), 256, 0, stream>>>(W_enc, ws);
    k_enc<<<64, 256, 0, stream>>>(b_enc, ws);
    k_dist_copy<<<8192, 256, 0, stream>>>(memory, out_mem, ws);
    k_final<<<1, 256, 0, stream>>>(x, count, ws, out);
}